// Round 1
// baseline (143.451 us; speedup 1.0000x reference)
//
#include <hip/hip_runtime.h>
#include <cstdint>
#include <cstddef>

typedef __bf16 bf16;
typedef __bf16 bf16x8 __attribute__((ext_vector_type(8)));
typedef __bf16 bf16x4 __attribute__((ext_vector_type(4)));
typedef float  f32x4  __attribute__((ext_vector_type(4)));

constexpr int Bb  = 2;
constexpr int Ss  = 2048;
constexpr int Hh  = 768;
constexpr int NHh = 12;
constexpr int DHh = 64;
constexpr int Mm  = Bb * Ss;   // 4096
constexpr int N3  = 3 * Hh;    // 2304
constexpr int QKW = 2 * Hh;    // 1536 (Q,K packed buffer row width)
constexpr float SCALE = 0.125f; // 64^-0.5

__device__ __forceinline__ void gload_lds16(void* lds, const void* g) {
  __builtin_amdgcn_global_load_lds(
      (__attribute__((address_space(1))) void*)(uintptr_t)g,
      (__attribute__((address_space(3))) void*)(uint32_t)(uintptr_t)lds,
      16, 0, 0);
}

__global__ void cvt_f32_bf16(const float* __restrict__ in, bf16* __restrict__ out, int n4) {
  int i = blockIdx.x * blockDim.x + threadIdx.x;
  int st = gridDim.x * blockDim.x;
  for (; i < n4; i += st) {
    float4 v = ((const float4*)in)[i];
    bf16x4 o;
    o[0] = (bf16)v.x; o[1] = (bf16)v.y; o[2] = (bf16)v.z; o[3] = (bf16)v.w;
    ((bf16x4*)out)[i] = o;
  }
}

// C = A[M,768] * Bw[N,768]^T. OUTMODE 0: bf16 out (Q,K region -> Cb stride CSTRIDE,
// V region -> VtG transposed [b][h][d][S]). OUTMODE 1: f32 out + bias, stride CSTRIDE.
template<int CSTRIDE, int OUTMODE>
__global__ __launch_bounds__(256, 2)
void gemm_bt(const bf16* __restrict__ A, const bf16* __restrict__ Bw,
             bf16* __restrict__ Cb, bf16* __restrict__ VtG,
             float* __restrict__ Cf, const float* __restrict__ bias)
{
  constexpr int K = 768;
  __shared__ bf16 As[128 * 32];
  __shared__ bf16 Bs[128 * 32];
  const int tid  = threadIdx.x;
  const int wid  = tid >> 6, lane = tid & 63;
  const int lr   = lane & 15, lk = lane >> 4;
  const int n0   = blockIdx.x * 128, m0 = blockIdx.y * 128;
  const int wm   = (wid >> 1) * 64, wn = (wid & 1) * 64;

  f32x4 acc[4][4] = {};

  // staging: thread t covers LDS bytes r*4096 + t*16  (row = r*64 + t/4, chunk (t&3)*16)
  const char* Ag = (const char*)(A  + (size_t)m0 * K) + (size_t)(tid >> 2) * (K * 2) + (tid & 3) * 16;
  const char* Bg = (const char*)(Bw + (size_t)n0 * K) + (size_t)(tid >> 2) * (K * 2) + (tid & 3) * 16;
  char* AsW = (char*)As + wid * 1024;
  char* BsW = (char*)Bs + wid * 1024;
  constexpr size_t rstep = (size_t)64 * K * 2;

  for (int kb = 0; kb < K; kb += 32) {
    gload_lds16(AsW,        Ag + (size_t)kb * 2);
    gload_lds16(AsW + 4096, Ag + rstep + (size_t)kb * 2);
    gload_lds16(BsW,        Bg + (size_t)kb * 2);
    gload_lds16(BsW + 4096, Bg + rstep + (size_t)kb * 2);
    __syncthreads();
    bf16x8 af[4], bfv[4];
#pragma unroll
    for (int i = 0; i < 4; ++i) {
      af[i]  = *(const bf16x8*)((const char*)As + ((wm + i * 16 + lr) * 32 + lk * 8) * 2);
      bfv[i] = *(const bf16x8*)((const char*)Bs + ((wn + i * 16 + lr) * 32 + lk * 8) * 2);
    }
#pragma unroll
    for (int i = 0; i < 4; ++i)
#pragma unroll
      for (int j = 0; j < 4; ++j)
        acc[i][j] = __builtin_amdgcn_mfma_f32_16x16x32_bf16(af[i], bfv[j], acc[i][j], 0, 0, 0);
    __syncthreads();
  }

  // D layout: row = lk*4 + r, col = lr (per m89/m91)
  if constexpr (OUTMODE == 1) {
#pragma unroll
    for (int i = 0; i < 4; ++i)
#pragma unroll
      for (int j = 0; j < 4; ++j) {
        const int n = n0 + wn + j * 16 + lr;
        const float bv = bias[n];
#pragma unroll
        for (int r = 0; r < 4; ++r) {
          const int m = m0 + wm + i * 16 + lk * 4 + r;
          Cf[(size_t)m * CSTRIDE + n] = acc[i][j][r] + bv;
        }
      }
  } else {
    if (n0 < QKW) {   // Q,K region -> packed [4096][1536] bf16
#pragma unroll
      for (int i = 0; i < 4; ++i)
#pragma unroll
        for (int j = 0; j < 4; ++j) {
          const int n = n0 + wn + j * 16 + lr;
#pragma unroll
          for (int r = 0; r < 4; ++r) {
            const int m = m0 + wm + i * 16 + lk * 4 + r;
            Cb[(size_t)m * CSTRIDE + n] = (bf16)acc[i][j][r];
          }
        }
    } else {          // V region -> VtG[b][h][d][s]
      const int bidx = m0 >> 11;
      const int s0 = (m0 & 2047) + wm + lk * 4;
#pragma unroll
      for (int i = 0; i < 4; ++i)
#pragma unroll
        for (int j = 0; j < 4; ++j) {
          const int colv = (n0 - QKW) + wn + j * 16 + lr;
          const int hh = colv >> 6, dd = colv & 63;
          bf16x4 pv;
#pragma unroll
          for (int r = 0; r < 4; ++r) pv[r] = (bf16)acc[i][j][r];
          *(bf16x4*)(VtG + (((size_t)(bidx * NHh + hh) * DHh + dd) << 11) + s0 + i * 16) = pv;
        }
    }
  }
}

// Flash attention: grid (S/64, NH, B), 256 threads (4 waves x 16 q-rows), KV block 64.
__global__ __launch_bounds__(256, 2)
void attn_fwd(const bf16* __restrict__ qk, const bf16* __restrict__ VtG,
              bf16* __restrict__ aout)
{
  __shared__ bf16 Ks[64 * 64];        // [kv][d], XOR-swizzled rows (128B)
  __shared__ bf16 Vs[64 * 64];        // [d][kv], XOR-swizzled rows
  __shared__ bf16 Ps[4][16 * 64];     // per-wave P, XOR-swizzled rows
  const int tid = threadIdx.x, wid = tid >> 6, lane = tid & 63;
  const int lr = lane & 15, lk = lane >> 4;
  const int q0 = blockIdx.x * 64 + wid * 16;
  const int h = blockIdx.y, b = blockIdx.z;

  // Q fragments (A-operand): row = lr, k(d) = lk*8..+7 (+32)
  const bf16* qrow = qk + (size_t)(b * Ss + q0 + lr) * QKW + h * DHh;
  const bf16x8 qf0 = *(const bf16x8*)(qrow + lk * 8);
  const bf16x8 qf1 = *(const bf16x8*)(qrow + 32 + lk * 8);

  float mrun[4], lrun[4];
  f32x4 oacc[4] = {};
#pragma unroll
  for (int r = 0; r < 4; ++r) { mrun[r] = -3.0e38f; lrun[r] = 0.f; }

  // staging: thread t covers LDS bytes rr*4096 + t*16 (row rr*32 + t/8, chunk (t&7)*16),
  // source pre-swizzled: chunk ^ ((row&7)<<4); rr*32 keeps row&7 invariant.
  const int strow = tid >> 3;
  const int stswz = ((tid & 7) * 16) ^ ((strow & 7) << 4);
  const char* KgT = (const char*)(qk + (size_t)b * Ss * QKW + Hh + h * DHh)
                    + (size_t)strow * (QKW * 2) + stswz;
  const char* VgT = (const char*)(VtG + (size_t)(b * NHh + h) * DHh * Ss)
                    + (size_t)strow * (Ss * 2) + stswz;
  char* KsW = (char*)Ks + wid * 1024;
  char* VsW = (char*)Vs + wid * 1024;
  char* Pw  = (char*)Ps[wid];
  const char* Pr = (const char*)Ps[wid] + lr * 128;

  for (int kv0 = 0; kv0 < Ss; kv0 += 64) {
#pragma unroll
    for (int rr = 0; rr < 2; ++rr) {
      gload_lds16(KsW + rr * 4096, KgT + (size_t)(kv0 + rr * 32) * (QKW * 2));
      gload_lds16(VsW + rr * 4096, VgT + (size_t)(rr * 32) * (Ss * 2) + kv0 * 2);
    }
    __syncthreads();

    // S = Q K^T : B-operand from Ks (col = kv = kvf*16+lr, k(d) = lk*8..)
    f32x4 sf[4];
#pragma unroll
    for (int kvf = 0; kvf < 4; ++kvf) {
      const int row = kvf * 16 + lr;
      const char* kb = (const char*)Ks + row * 128;
      const int sw = (row & 7) << 4;
      bf16x8 k0 = *(const bf16x8*)(kb + ((lk * 16) ^ sw));
      bf16x8 k1 = *(const bf16x8*)(kb + ((64 + lk * 16) ^ sw));
      f32x4 s = {};
      s = __builtin_amdgcn_mfma_f32_16x16x32_bf16(qf0, k0, s, 0, 0, 0);
      s = __builtin_amdgcn_mfma_f32_16x16x32_bf16(qf1, k1, s, 0, 0, 0);
      sf[kvf] = s * SCALE;
    }

    // online softmax; S rows live at q = lk*4 + r, cols across 16-lane groups
    float mt[4];
#pragma unroll
    for (int r = 0; r < 4; ++r)
      mt[r] = fmaxf(fmaxf(sf[0][r], sf[1][r]), fmaxf(sf[2][r], sf[3][r]));
#pragma unroll
    for (int off = 1; off < 16; off <<= 1)
#pragma unroll
      for (int r = 0; r < 4; ++r)
        mt[r] = fmaxf(mt[r], __shfl_xor(mt[r], off, 64));
    float alpha[4], rs[4] = {0.f, 0.f, 0.f, 0.f};
#pragma unroll
    for (int r = 0; r < 4; ++r) {
      const float mn = fmaxf(mrun[r], mt[r]);
      alpha[r] = __expf(mrun[r] - mn);
      mrun[r] = mn;
    }
#pragma unroll
    for (int kvf = 0; kvf < 4; ++kvf) {
      const int cb = (kvf * 16 + lr) * 2;
#pragma unroll
      for (int r = 0; r < 4; ++r) {
        const float p = __expf(sf[kvf][r] - mrun[r]);
        rs[r] += p;
        const int row = lk * 4 + r;
        *(bf16*)(Pw + row * 128 + (cb ^ ((row & 7) << 4))) = (bf16)p;
      }
    }
#pragma unroll
    for (int off = 1; off < 16; off <<= 1)
#pragma unroll
      for (int r = 0; r < 4; ++r)
        rs[r] += __shfl_xor(rs[r], off, 64);
#pragma unroll
    for (int r = 0; r < 4; ++r) lrun[r] = lrun[r] * alpha[r] + rs[r];
    __syncthreads();   // P visible to all lanes of the wave; Ps region per-wave

    // O = O*alpha + P V  (A = P: row = lr, k = kv; B = V from Vs[d][kv])
    bf16x8 pa0, pa1;
    {
      const int sw = (lr & 7) << 4;
      pa0 = *(const bf16x8*)(Pr + ((lk * 16) ^ sw));
      pa1 = *(const bf16x8*)(Pr + ((64 + lk * 16) ^ sw));
    }
#pragma unroll
    for (int df = 0; df < 4; ++df) {
      const int row = df * 16 + lr;
      const char* vb = (const char*)Vs + row * 128;
      const int sw = (row & 7) << 4;
      bf16x8 v0 = *(const bf16x8*)(vb + ((lk * 16) ^ sw));
      bf16x8 v1 = *(const bf16x8*)(vb + ((64 + lk * 16) ^ sw));
      f32x4 o = oacc[df];
#pragma unroll
      for (int r = 0; r < 4; ++r) o[r] *= alpha[r];
      o = __builtin_amdgcn_mfma_f32_16x16x32_bf16(pa0, v0, o, 0, 0, 0);
      o = __builtin_amdgcn_mfma_f32_16x16x32_bf16(pa1, v1, o, 0, 0, 0);
      oacc[df] = o;
    }
    __syncthreads();   // protect Ks/Vs/Ps before next staging
  }

  float inv[4];
#pragma unroll
  for (int r = 0; r < 4; ++r) inv[r] = 1.0f / lrun[r];
  bf16* orow = aout + (size_t)(b * Ss + q0) * Hh + h * DHh;
#pragma unroll
  for (int df = 0; df < 4; ++df)
#pragma unroll
    for (int r = 0; r < 4; ++r)
      orow[(size_t)(lk * 4 + r) * Hh + df * 16 + lr] = (bf16)(oacc[df][r] * inv[r]);
}

extern "C" void kernel_launch(void* const* d_in, const int* in_sizes, int n_in,
                              void* d_out, int out_size, void* d_ws, size_t ws_size,
                              hipStream_t stream) {
  const float* x     = (const float*)d_in[0];
  const float* w_qkv = (const float*)d_in[1];
  const float* w_out = (const float*)d_in[2];
  const float* b_out = (const float*)d_in[3];
  char* ws = (char*)d_ws;
  // ws layout (bytes), all 256-aligned:
  bf16* xb    = (bf16*)(ws + 0);          //  4096*768*2  = 6291456
  bf16* wqkvb = (bf16*)(ws + 6291456);    //  2304*768*2  = 3538944
  bf16* woutb = (bf16*)(ws + 9830400);    //   768*768*2  = 1179648
  bf16* qkb   = (bf16*)(ws + 11010048);   //  4096*1536*2 = 12582912
  bf16* VtG   = (bf16*)(ws + 23592960);   //  24*64*2048*2 = 6291456
  bf16* aoutb = (bf16*)(ws + 29884416);   //  4096*768*2  = 6291456  (end 36175872)

  cvt_f32_bf16<<<3072, 256, 0, stream>>>(x,     xb,    Mm * Hh / 4);
  cvt_f32_bf16<<<1728, 256, 0, stream>>>(w_qkv, wqkvb, N3 * Hh / 4);
  cvt_f32_bf16<<<576,  256, 0, stream>>>(w_out, woutb, Hh * Hh / 4);

  gemm_bt<QKW, 0><<<dim3(18, 32), 256, 0, stream>>>(xb, wqkvb, qkb, VtG, nullptr, nullptr);
  attn_fwd<<<dim3(Ss / 64, NHh, Bb), 256, 0, stream>>>(qkb, VtG, aoutb);
  gemm_bt<Hh, 1><<<dim3(6, 32), 256, 0, stream>>>(aoutb, woutb, nullptr, nullptr,
                                                  (float*)d_out, b_out);
}

// Round 3
// 118.028 us; speedup vs baseline: 1.2154x; 1.2154x over previous
//
#include <hip/hip_runtime.h>
#include <cstdint>
#include <cstddef>

typedef __bf16 bf16;
typedef __bf16 bf16x8 __attribute__((ext_vector_type(8)));
typedef __bf16 bf16x4 __attribute__((ext_vector_type(4)));
typedef float  f32x4  __attribute__((ext_vector_type(4)));
typedef float  f32x16 __attribute__((ext_vector_type(16)));

constexpr int Bb  = 2;
constexpr int Ss  = 2048;
constexpr int Hh  = 768;
constexpr int NHh = 12;
constexpr int DHh = 64;
constexpr int Mm  = Bb * Ss;   // 4096
constexpr int N3  = 3 * Hh;    // 2304
constexpr int QKW = 2 * Hh;    // 1536 (Q,K packed buffer row width)

__device__ __forceinline__ float fexp2(float x) { return __builtin_amdgcn_exp2f(x); }

__device__ __forceinline__ void gload_lds16(void* lds, const void* g) {
  __builtin_amdgcn_global_load_lds(
      (__attribute__((address_space(1))) void*)(uintptr_t)g,
      (__attribute__((address_space(3))) void*)(uint32_t)(uintptr_t)lds,
      16, 0, 0);
}

__global__ void cvt_f32_bf16(const float* __restrict__ in, bf16* __restrict__ out, int n4) {
  int i = blockIdx.x * blockDim.x + threadIdx.x;
  int st = gridDim.x * blockDim.x;
  for (; i < n4; i += st) {
    float4 v = ((const float4*)in)[i];
    bf16x4 o;
    o[0] = (bf16)v.x; o[1] = (bf16)v.y; o[2] = (bf16)v.z; o[3] = (bf16)v.w;
    ((bf16x4*)out)[i] = o;
  }
}

// C = A[M,768] * Bw[N,768]^T. OUTMODE 0: bf16 out (Q,K region -> Cb stride CSTRIDE,
// V region -> VtG transposed [b][h][d][S]). OUTMODE 1: f32 out + bias, stride CSTRIDE.
template<int CSTRIDE, int OUTMODE>
__global__ __launch_bounds__(256, 2)
void gemm_bt(const bf16* __restrict__ A, const bf16* __restrict__ Bw,
             bf16* __restrict__ Cb, bf16* __restrict__ VtG,
             float* __restrict__ Cf, const float* __restrict__ bias)
{
  constexpr int K = 768;
  __shared__ bf16 As[128 * 32];
  __shared__ bf16 Bs[128 * 32];
  const int tid  = threadIdx.x;
  const int wid  = tid >> 6, lane = tid & 63;
  const int lr   = lane & 15, lk = lane >> 4;
  const int n0   = blockIdx.x * 128, m0 = blockIdx.y * 128;
  const int wm   = (wid >> 1) * 64, wn = (wid & 1) * 64;

  f32x4 acc[4][4] = {};

  const char* Ag = (const char*)(A  + (size_t)m0 * K) + (size_t)(tid >> 2) * (K * 2) + (tid & 3) * 16;
  const char* Bg = (const char*)(Bw + (size_t)n0 * K) + (size_t)(tid >> 2) * (K * 2) + (tid & 3) * 16;
  char* AsW = (char*)As + wid * 1024;
  char* BsW = (char*)Bs + wid * 1024;
  constexpr size_t rstep = (size_t)64 * K * 2;

  for (int kb = 0; kb < K; kb += 32) {
    gload_lds16(AsW,        Ag + (size_t)kb * 2);
    gload_lds16(AsW + 4096, Ag + rstep + (size_t)kb * 2);
    gload_lds16(BsW,        Bg + (size_t)kb * 2);
    gload_lds16(BsW + 4096, Bg + rstep + (size_t)kb * 2);
    __syncthreads();
    bf16x8 af[4], bfv[4];
#pragma unroll
    for (int i = 0; i < 4; ++i) {
      af[i]  = *(const bf16x8*)((const char*)As + ((wm + i * 16 + lr) * 32 + lk * 8) * 2);
      bfv[i] = *(const bf16x8*)((const char*)Bs + ((wn + i * 16 + lr) * 32 + lk * 8) * 2);
    }
#pragma unroll
    for (int i = 0; i < 4; ++i)
#pragma unroll
      for (int j = 0; j < 4; ++j)
        acc[i][j] = __builtin_amdgcn_mfma_f32_16x16x32_bf16(af[i], bfv[j], acc[i][j], 0, 0, 0);
    __syncthreads();
  }

  if constexpr (OUTMODE == 1) {
#pragma unroll
    for (int i = 0; i < 4; ++i)
#pragma unroll
      for (int j = 0; j < 4; ++j) {
        const int n = n0 + wn + j * 16 + lr;
        const float bv = bias[n];
#pragma unroll
        for (int r = 0; r < 4; ++r) {
          const int m = m0 + wm + i * 16 + lk * 4 + r;
          Cf[(size_t)m * CSTRIDE + n] = acc[i][j][r] + bv;
        }
      }
  } else {
    if (n0 < QKW) {
#pragma unroll
      for (int i = 0; i < 4; ++i)
#pragma unroll
        for (int j = 0; j < 4; ++j) {
          const int n = n0 + wn + j * 16 + lr;
#pragma unroll
          for (int r = 0; r < 4; ++r) {
            const int m = m0 + wm + i * 16 + lk * 4 + r;
            Cb[(size_t)m * CSTRIDE + n] = (bf16)acc[i][j][r];
          }
        }
    } else {
      const int bidx = m0 >> 11;
      const int s0 = (m0 & 2047) + wm + lk * 4;
#pragma unroll
      for (int i = 0; i < 4; ++i)
#pragma unroll
        for (int j = 0; j < 4; ++j) {
          const int colv = (n0 - QKW) + wn + j * 16 + lr;
          const int hh = colv >> 6, dd = colv & 63;
          bf16x4 pv;
#pragma unroll
          for (int r = 0; r < 4; ++r) pv[r] = (bf16)acc[i][j][r];
          *(bf16x4*)(VtG + (((size_t)(bidx * NHh + hh) * DHh + dd) << 11) + s0 + i * 16) = pv;
        }
    }
  }
}

// Flash attention v2: grid (32 qblocks, 24 b*h), 256 threads.
// 4 waves = 2 q-halves (wid&1, 32 q each) x 2 kv-halves (wid>>1, 1024 kv each).
// 32x32x16 MFMA, swapped QK^T (S^T), in-register softmax (base-2), P in regs,
// V direct from L2 (VtG [d][s]), K double-buffered in LDS, 1 barrier/iter.
// End: kv-halves merged through LDS.
__global__ __launch_bounds__(256, 3)
void attn_fwd2(const bf16* __restrict__ qk, const bf16* __restrict__ VtG,
               bf16* __restrict__ aout)
{
  __shared__ __align__(16) char lds[32768];  // K tiles: grp*16384 + buf*8192
  const int tid  = threadIdx.x;
  const int wid  = tid >> 6, lane = tid & 63;
  const int lq   = lane & 31, hi = lane >> 5;
  const int qh   = wid & 1, grp = wid >> 1;
  const int bh   = blockIdx.y;
  const int b    = bh / NHh, h = bh % NHh;
  const int q0   = blockIdx.x * 64 + qh * 32;
  const int kvbase = grp * 1024;

  // Q B-fragments, pre-scaled by SCALE*log2(e) (softmax runs in base-2 domain)
  constexpr float Cs = 0.18033688011112042f;  // 0.125 * log2(e)
  const bf16* qrow = qk + (size_t)(b * Ss + q0 + lq) * QKW + h * DHh;
  bf16x8 qf[4];
#pragma unroll
  for (int j = 0; j < 4; ++j) {
    bf16x8 t = *(const bf16x8*)(qrow + j * 16 + hi * 8);
#pragma unroll
    for (int e = 0; e < 8; ++e) t[e] = (bf16)((float)t[e] * Cs);
    qf[j] = t;
  }

  // K staging geometry: wave covers LDS [grp*16384 + buf*8192 + qh*4096 + c*1024),
  // lane L -> +L*16 (linear dest). row = qh*32 + c*8 + (L>>3); global source column
  // pre-swizzled by ((row&7)<<4) so swizzled ds_reads see logical data (rule #21).
  const int strow = qh * 32 + (lane >> 3);
  const int stcol = ((lane & 7) * 16) ^ (((lane >> 3) & 7) << 4);
  const char* Kg0 = (const char*)(qk + (size_t)(b * Ss) * QKW + Hh + h * DHh)
                    + (size_t)strow * (QKW * 2) + stcol;
  auto stageK = [&](int buf, int kvt) {
    char* db = lds + grp * 16384 + buf * 8192 + qh * 4096;
    const char* sg = Kg0 + (size_t)kvt * (QKW * 2);
#pragma unroll
    for (int c = 0; c < 4; ++c)
      gload_lds16(db + c * 1024, sg + (size_t)(c * 8) * (QKW * 2));
  };

  const bf16* Vbase = VtG + (size_t)bh * DHh * Ss;  // [d][s]

  float mrun = -1.0e30f, lrun = 0.f;
  f32x16 oacc[2] = {};

  stageK(0, kvbase);
  __syncthreads();

  for (int i = 0; i < 16; ++i) {
    const int cur = i & 1;
    const int kv0 = kvbase + i * 64;

    // V^T A-fragments direct from global (L2-hit); issued early, complete under softmax
    bf16x8 vf[4][2];
#pragma unroll
    for (int s = 0; s < 4; ++s)
#pragma unroll
      for (int dc = 0; dc < 2; ++dc)
        vf[s][dc] = *(const bf16x8*)(Vbase + (size_t)(dc * 32 + lq) * Ss + kv0 + s * 16 + hi * 8);

    // prefetch next K tile into the other buffer
    if (i < 15) stageK(cur ^ 1, kvbase + (i + 1) * 64);

    // S^T = K * Q^T  (D[kv][q]; lane: q = lq, kv = (r&3)+8*(r>>2)+4*hi +32*kvc)
    f32x16 sacc[2];
#pragma unroll
    for (int kvc = 0; kvc < 2; ++kvc) {
      f32x16 s = {};
      const int row = kvc * 32 + lq;
      const char* kb = lds + grp * 16384 + cur * 8192 + row * 128;
      const int sw = (lq & 7) << 4;
#pragma unroll
      for (int j = 0; j < 4; ++j) {
        bf16x8 kf = *(const bf16x8*)(kb + ((j * 32 + hi * 16) ^ sw));
        s = __builtin_amdgcn_mfma_f32_32x32x16_bf16(kf, qf[j], s, 0, 0, 0);
      }
      sacc[kvc] = s;
    }

    // online softmax (base 2), in-lane over 32 values + lane^32 exchange
    float mt = sacc[0][0];
#pragma unroll
    for (int kvc = 0; kvc < 2; ++kvc)
#pragma unroll
      for (int r = 0; r < 16; ++r) mt = fmaxf(mt, sacc[kvc][r]);
    mt = fmaxf(mt, __shfl_xor(mt, 32, 64));
    const float mn = fmaxf(mrun, mt);
    const float al = fexp2(mrun - mn);
    mrun = mn;
    float rs = 0.f;
#pragma unroll
    for (int kvc = 0; kvc < 2; ++kvc)
#pragma unroll
      for (int r = 0; r < 16; ++r) {
        const float p = fexp2(sacc[kvc][r] - mn);
        sacc[kvc][r] = p;
        rs += p;
      }
    rs += __shfl_xor(rs, 32, 64);
    lrun = lrun * al + rs;

    // pack P to bf16 pairs: w[kvc][m] = (p[2m], p[2m+1]) -> kv pairs within block
    uint32_t w[2][8];
#pragma unroll
    for (int kvc = 0; kvc < 2; ++kvc)
#pragma unroll
      for (int m = 0; m < 8; ++m) {
        union { bf16 hh[2]; uint32_t u; } cv;
        cv.hh[0] = (bf16)sacc[kvc][2 * m];
        cv.hh[1] = (bf16)sacc[kvc][2 * m + 1];
        w[kvc][m] = cv.u;
      }

    // rescale O accumulator
#pragma unroll
    for (int dc = 0; dc < 2; ++dc)
#pragma unroll
      for (int r = 0; r < 16; ++r) oacc[dc][r] *= al;

    // drain V regs + K(next) stage (vmcnt0) and sync -> K(next) visible block-wide
    __syncthreads();

    // build P^T B-fragments (lane needs kv = 8*hi + 0..7 of each 16-kv sub-block)
    // own regs hold kv {4hi+0..3, 8+4hi+0..3}; other half via lane^32 exchange
#pragma unroll
    for (int s = 0; s < 4; ++s) {
      const int kvc = s >> 1, sb = s & 1;
      const uint32_t lo0 = w[kvc][4 * sb + 0], lo1 = w[kvc][4 * sb + 1];
      const uint32_t hi0 = w[kvc][4 * sb + 2], hi1 = w[kvc][4 * sb + 3];
      const uint32_t sxlo0 = (uint32_t)__shfl_xor((int)lo0, 32, 64);
      const uint32_t sxlo1 = (uint32_t)__shfl_xor((int)lo1, 32, 64);
      const uint32_t sxhi0 = (uint32_t)__shfl_xor((int)hi0, 32, 64);
      const uint32_t sxhi1 = (uint32_t)__shfl_xor((int)hi1, 32, 64);
      union { uint32_t u[4]; bf16x8 v; } pf;
      pf.u[0] = hi ? sxhi0 : lo0;
      pf.u[1] = hi ? sxhi1 : lo1;
      pf.u[2] = hi ? hi0 : sxlo0;
      pf.u[3] = hi ? hi1 : sxlo1;
      // O^T += V^T * P^T   (D[d][q]; lane: q = lq, d = (r&3)+8*(r>>2)+4*hi +32*dc)
#pragma unroll
      for (int dc = 0; dc < 2; ++dc)
        oacc[dc] = __builtin_amdgcn_mfma_f32_32x32x16_bf16(vf[s][dc], pf.v, oacc[dc], 0, 0, 0);
    }
  }

  // merge kv-halves: grp1 exports (O, m, l) via LDS, grp0 combines and writes
  if (grp == 1) {
    char* mb = lds + qh * 8704;
#pragma unroll
    for (int dc = 0; dc < 2; ++dc)
#pragma unroll
      for (int rr = 0; rr < 4; ++rr) {
        f32x4 t;
#pragma unroll
        for (int e = 0; e < 4; ++e) t[e] = oacc[dc][rr * 4 + e];
        *(f32x4*)(mb + (dc * 4 + rr) * 1024 + lane * 16) = t;
      }
    *(float*)(mb + 8192 + lane * 8)     = mrun;
    *(float*)(mb + 8192 + lane * 8 + 4) = lrun;
  }
  __syncthreads();
  if (grp == 0) {
    const char* mb = lds + qh * 8704;
    const float m2 = *(const float*)(mb + 8192 + lane * 8);
    const float l2 = *(const float*)(mb + 8192 + lane * 8 + 4);
    const float mM = fmaxf(mrun, m2);
    const float c1 = fexp2(mrun - mM), c2 = fexp2(m2 - mM);
    const float linv = 1.0f / (lrun * c1 + l2 * c2);
    bf16* orow = aout + (size_t)(b * Ss + q0 + lq) * Hh + h * DHh;
#pragma unroll
    for (int dc = 0; dc < 2; ++dc)
#pragma unroll
      for (int rr = 0; rr < 4; ++rr) {
        const f32x4 o2 = *(const f32x4*)(mb + (dc * 4 + rr) * 1024 + lane * 16);
        bf16x4 ov;
#pragma unroll
        for (int e = 0; e < 4; ++e)
          ov[e] = (bf16)((oacc[dc][rr * 4 + e] * c1 + o2[e] * c2) * linv);
        *(bf16x4*)(orow + dc * 32 + rr * 8 + hi * 4) = ov;
      }
  }
}

extern "C" void kernel_launch(void* const* d_in, const int* in_sizes, int n_in,
                              void* d_out, int out_size, void* d_ws, size_t ws_size,
                              hipStream_t stream) {
  const float* x     = (const float*)d_in[0];
  const float* w_qkv = (const float*)d_in[1];
  const float* w_out = (const float*)d_in[2];
  const float* b_out = (const float*)d_in[3];
  char* ws = (char*)d_ws;
  bf16* xb    = (bf16*)(ws + 0);
  bf16* wqkvb = (bf16*)(ws + 6291456);
  bf16* woutb = (bf16*)(ws + 9830400);
  bf16* qkb   = (bf16*)(ws + 11010048);
  bf16* VtG   = (bf16*)(ws + 23592960);
  bf16* aoutb = (bf16*)(ws + 29884416);

  cvt_f32_bf16<<<3072, 256, 0, stream>>>(x,     xb,    Mm * Hh / 4);
  cvt_f32_bf16<<<1728, 256, 0, stream>>>(w_qkv, wqkvb, N3 * Hh / 4);
  cvt_f32_bf16<<<576,  256, 0, stream>>>(w_out, woutb, Hh * Hh / 4);

  gemm_bt<QKW, 0><<<dim3(18, 32), 256, 0, stream>>>(xb, wqkvb, qkb, VtG, nullptr, nullptr);
  attn_fwd2<<<dim3(32, 24), 256, 0, stream>>>(qkb, VtG, aoutb);
  gemm_bt<Hh, 1><<<dim3(6, 32), 256, 0, stream>>>(aoutb, woutb, nullptr, nullptr,
                                                  (float*)d_out, b_out);
}